// Round 5
// baseline (97.632 us; speedup 1.0000x reference)
//
#include <hip/hip_runtime.h>

// Problem constants (fixed by the reference)
constexpr int BN  = 64;          // batch
constexpr int HH  = 28;          // height
constexpr int WW  = 28;          // width
constexpr int CC  = 1024;        // channels
constexpr int HWP = HH * WW;     // 784 spatial positions
constexpr int CQ  = CC / 4;      // 256 float4s per spatial position row
constexpr float TAU = 0.5f / 784.0f;

// Native clang vector type (required by __builtin_nontemporal_store; same
// 16-byte layout as float4).
typedef float f32x4 __attribute__((ext_vector_type(4)));

__device__ __forceinline__ int iabs(int x) { return x < 0 ? -x : x; }

// ---------------------------------------------------------------------------
// Fused kernel, small-block variant: one block = (batch b, 16-channel group).
// 256 threads: channel-quad q = t&3 (4 channels), position split s3 = t>>2.
// Thread owns positions {s3 + 64k}, k = 0..11 (+k=12 if s3<16).
// Rationale vs the 512-thread version: VGPR ~36-40 and LDS ~9 KB allow up to
// 8 blocks/CU resident. Blocks phase-lock internally (load -> reduce ->
// store), so many independently-phased small blocks per CU keep HBM busy
// where 2 big blocks could not (measured 54% occupancy, 4.4 TB/s effective).
//   Phase A: 13 independent float4 loads (coalesced 64 B segments), inline
//            per-thread argmax (strict '>', ascending positions).
//   Phase B: two-stage LDS reduce, (v > bv) || (v == bv && x < bx) tie-break
//            -> exact jnp.argmax first-occurrence semantics.
//   Phase C: mask + nontemporal store (compiler may re-load the input from
//            L3 here rather than hold registers; that is fine and overlapped).
// Mask: tau * max(1 - 4d/28, -1) == max(fma(d, -tau/7, tau), -tau) (<= ~2ulp
// of tau deviation; measured absmax 7.6e-6 vs threshold 6.9e-5).
// ---------------------------------------------------------------------------
__global__ __launch_bounds__(256) void fused_mask_kernel(
    const f32x4* __restrict__ in4, f32x4* __restrict__ out4) {
  __shared__ float s_pv[64][16];
  __shared__ int   s_pi[64][16];
  __shared__ float s2v[8][16];
  __shared__ int   s2i[8][16];
  __shared__ int   s_peak[16];

  const int t  = threadIdx.x;
  const int q  = t & 3;          // channel quad within the 16-ch group
  const int s3 = t >> 2;         // position split 0..63
  const int b  = blockIdx.x >> 6;
  const int cg = blockIdx.x & 63;

  const size_t base = ((size_t)b * HWP + s3) * CQ + cg * 4 + q;
  const f32x4* src = in4 + base;
  f32x4*       dst = out4 + base;
  constexpr size_t KSTR = (size_t)64 * CQ;   // 64 positions per k-step

  const bool tail = (s3 < 16);   // positions 768..783

#define LIST12(X) X(0) X(1) X(2) X(3) X(4) X(5) X(6) X(7) X(8) X(9) X(10) X(11)

  // ---- Phase A: 12-13 independent loads ----
#define LOADK(k) const f32x4 vv##k = src[(size_t)(k) * KSTR];
  LIST12(LOADK)
#undef LOADK
  f32x4 vv12 = {0.0f, 0.0f, 0.0f, 0.0f};
  if (tail) vv12 = src[(size_t)12 * KSTR];

  // Inline per-thread argmax (4 channels), ascending positions, strict '>'.
  float bm0 = -__builtin_inff(), bm1 = bm0, bm2 = bm0, bm3 = bm0;
  int   bi0 = 0, bi1 = 0, bi2 = 0, bi3 = 0;
#define AMAXK(k) { const int p = s3 + 64 * (k); \
    if (vv##k.x > bm0) { bm0 = vv##k.x; bi0 = p; } \
    if (vv##k.y > bm1) { bm1 = vv##k.y; bi1 = p; } \
    if (vv##k.z > bm2) { bm2 = vv##k.z; bi2 = p; } \
    if (vv##k.w > bm3) { bm3 = vv##k.w; bi3 = p; } }
  LIST12(AMAXK)
#undef AMAXK
  if (tail) {
    const int p = s3 + 768;
    if (vv12.x > bm0) { bm0 = vv12.x; bi0 = p; }
    if (vv12.y > bm1) { bm1 = vv12.y; bi1 = p; }
    if (vv12.z > bm2) { bm2 = vv12.z; bi2 = p; }
    if (vv12.w > bm3) { bm3 = vv12.w; bi3 = p; }
  }

  // ---- Phase B: two-stage reduce with first-occurrence tie-break ----
  const int c0 = q * 4;
  s_pv[s3][c0 + 0] = bm0; s_pi[s3][c0 + 0] = bi0;
  s_pv[s3][c0 + 1] = bm1; s_pi[s3][c0 + 1] = bi1;
  s_pv[s3][c0 + 2] = bm2; s_pi[s3][c0 + 2] = bi2;
  s_pv[s3][c0 + 3] = bm3; s_pi[s3][c0 + 3] = bi3;
  __syncthreads();

  if (t < 128) {
    const int c = t & 15, g = t >> 4;   // 8 groups of 8 splits
    float bv = s_pv[g * 8][c];
    int   bx = s_pi[g * 8][c];
    #pragma unroll
    for (int u = 1; u < 8; ++u) {
      const float v = s_pv[g * 8 + u][c];
      const int   x = s_pi[g * 8 + u][c];
      if (v > bv || (v == bv && x < bx)) { bv = v; bx = x; }
    }
    s2v[g][c] = bv; s2i[g][c] = bx;
  }
  __syncthreads();
  if (t < 16) {
    float bv = s2v[0][t];
    int   bx = s2i[0][t];
    #pragma unroll
    for (int g = 1; g < 8; ++g) {
      const float v = s2v[g][t];
      const int   x = s2i[g][t];
      if (v > bv || (v == bv && x < bx)) { bv = v; bx = x; }
    }
    const int im = bx / 28;
    s_peak[t] = (im << 8) | (bx - im * 28);
  }
  __syncthreads();

  // ---- Phase C: mask + nontemporal store ----
  const int pk0 = s_peak[c0 + 0], pk1 = s_peak[c0 + 1];
  const int pk2 = s_peak[c0 + 2], pk3 = s_peak[c0 + 3];
  const int im0 = pk0 >> 8, jm0 = pk0 & 255;
  const int im1 = pk1 >> 8, jm1 = pk1 & 255;
  const int im2 = pk2 >> 8, jm2 = pk2 & 255;
  const int im3 = pk3 >> 8, jm3 = pk3 & 255;

  int i = s3 / 28;
  int j = s3 - i * 28;
  constexpr float MS = -(TAU / 7.0f);

#define APPLYK(k) { f32x4 o; \
    o.x = vv##k.x * fmaxf(fmaf((float)(iabs(i - im0) + iabs(j - jm0)), MS, TAU), -TAU); \
    o.y = vv##k.y * fmaxf(fmaf((float)(iabs(i - im1) + iabs(j - jm1)), MS, TAU), -TAU); \
    o.z = vv##k.z * fmaxf(fmaf((float)(iabs(i - im2) + iabs(j - jm2)), MS, TAU), -TAU); \
    o.w = vv##k.w * fmaxf(fmaf((float)(iabs(i - im3) + iabs(j - jm3)), MS, TAU), -TAU); \
    __builtin_nontemporal_store(o, dst + (size_t)(k) * KSTR); \
    j += 8; i += 2; if (j >= 28) { j -= 28; ++i; } }   // p += 64 -> (i,j) update
  LIST12(APPLYK)
#undef APPLYK
  if (tail) {
    f32x4 o;
    o.x = vv12.x * fmaxf(fmaf((float)(iabs(i - im0) + iabs(j - jm0)), MS, TAU), -TAU);
    o.y = vv12.y * fmaxf(fmaf((float)(iabs(i - im1) + iabs(j - jm1)), MS, TAU), -TAU);
    o.z = vv12.z * fmaxf(fmaf((float)(iabs(i - im2) + iabs(j - jm2)), MS, TAU), -TAU);
    o.w = vv12.w * fmaxf(fmaf((float)(iabs(i - im3) + iabs(j - jm3)), MS, TAU), -TAU);
    __builtin_nontemporal_store(o, dst + (size_t)12 * KSTR);
  }
#undef LIST12
}

extern "C" void kernel_launch(void* const* d_in, const int* in_sizes, int n_in,
                              void* d_out, int out_size, void* d_ws, size_t ws_size,
                              hipStream_t stream) {
  const f32x4* in4  = (const f32x4*)d_in[0];
  f32x4*       out4 = (f32x4*)d_out;
  // One block per (batch, 16-channel group): 64 x 64 = 4096 blocks, 256 thr.
  fused_mask_kernel<<<BN * 64, 256, 0, stream>>>(in4, out4);
}

// Round 6
// 76.661 us; speedup vs baseline: 1.2736x; 1.2736x over previous
//
#include <hip/hip_runtime.h>

// Problem constants (fixed by the reference)
constexpr int BN  = 64;          // batch
constexpr int HH  = 28;          // height
constexpr int WW  = 28;          // width
constexpr int CC  = 1024;        // channels
constexpr int HWP = HH * WW;     // 784 spatial positions
constexpr int CQ  = CC / 4;      // 256 float4s per spatial position row
constexpr float TAU = 0.5f / 784.0f;

constexpr int SPL = 112;         // position splits per block (784 = 112 * 7)
constexpr int KN  = 7;           // float4s owned per thread (exactly, no tail)

// Native clang vector type (required by __builtin_nontemporal_store; same
// 16-byte layout as float4).
typedef float f32x4 __attribute__((ext_vector_type(4)));

__device__ __forceinline__ int iabs(int x) { return x < 0 ? -x : x; }

// ---------------------------------------------------------------------------
// Fused kernel, register-pinned variant.
// Block = (batch b, 32-channel group cg): 896 threads = 112 splits x 8 quads.
//   q  = t & 7  -> channel quad; 8 quads x 16 B = 128 B per position per wave
//                  (full L2 lines consumed by ONE block — round-5's 64 B
//                  split doubled FETCH, reverted).
//   s3 = t >> 3 -> position split; thread owns p = s3 + 112k, k = 0..6.
// 112 = 4*28, so all 7 positions share j = s3 % 28 and i = s3/28 + 4k:
// per-channel |j - jm| is hoisted out of the store loop.
// The 7 loaded f32x4s are PINNED via empty asm ("+v") — the compiler cannot
// rematerialize the loads in phase C (round 4: VGPR=36 proved it re-read
// 205 MB through L2/L3; that redundant fabric traffic is what we remove).
// Phase B: two-stage LDS reduce with (v > bv) || (v == bv && x < bx)
// tie-break -> exact jnp.argmax first-occurrence semantics.
// Mask: tau * max(1 - 4d/28, -1) == max(fma(d, -tau/7, tau), -tau)
// (~2 ulp of tau; measured absmax 7.6e-6 vs threshold 6.9e-5).
// __launch_bounds__(896, 7): 14-wave blocks, force VGPR <= ~73 so 2 blocks/CU.
// ---------------------------------------------------------------------------
__global__ __launch_bounds__(896, 7) void fused_mask_kernel(
    const f32x4* __restrict__ in4, f32x4* __restrict__ out4) {
  __shared__ float s_pv[SPL][32];
  __shared__ int   s_pi[SPL][32];
  __shared__ float s2v[14][32];
  __shared__ int   s2i[14][32];
  __shared__ int   s_peak[32];

  const int t  = threadIdx.x;
  const int q  = t & 7;           // channel quad within the 32-ch group
  const int s3 = t >> 3;          // position split 0..111
  const int b  = blockIdx.x >> 5; // 32 channel-groups per batch
  const int cg = blockIdx.x & 31;

  const size_t base = ((size_t)b * HWP + s3) * CQ + cg * 8 + q;
  const f32x4* src = in4 + base;
  f32x4*       dst = out4 + base;
  constexpr size_t KSTR = (size_t)SPL * CQ;   // 112 positions per k-step

  // ---- Phase A: 7 independent loads, pinned in registers ----
  f32x4 vv0 = src[0 * KSTR];
  f32x4 vv1 = src[1 * KSTR];
  f32x4 vv2 = src[2 * KSTR];
  f32x4 vv3 = src[3 * KSTR];
  f32x4 vv4 = src[4 * KSTR];
  f32x4 vv5 = src[5 * KSTR];
  f32x4 vv6 = src[6 * KSTR];
  asm volatile("" : "+v"(vv0), "+v"(vv1), "+v"(vv2), "+v"(vv3),
                    "+v"(vv4), "+v"(vv5), "+v"(vv6));

  // Inline per-thread argmax (4 channels), ascending k -> ascending p.
  float bm0 = -__builtin_inff(), bm1 = bm0, bm2 = bm0, bm3 = bm0;
  int   bi0 = s3, bi1 = s3, bi2 = s3, bi3 = s3;
#define AMAXK(k) { const int p = s3 + SPL * (k); \
    if (vv##k.x > bm0) { bm0 = vv##k.x; bi0 = p; } \
    if (vv##k.y > bm1) { bm1 = vv##k.y; bi1 = p; } \
    if (vv##k.z > bm2) { bm2 = vv##k.z; bi2 = p; } \
    if (vv##k.w > bm3) { bm3 = vv##k.w; bi3 = p; } }
  AMAXK(0) AMAXK(1) AMAXK(2) AMAXK(3) AMAXK(4) AMAXK(5) AMAXK(6)
#undef AMAXK

  // ---- Phase B: two-stage reduce with first-occurrence tie-break ----
  const int c0 = q * 4;
  s_pv[s3][c0 + 0] = bm0; s_pi[s3][c0 + 0] = bi0;
  s_pv[s3][c0 + 1] = bm1; s_pi[s3][c0 + 1] = bi1;
  s_pv[s3][c0 + 2] = bm2; s_pi[s3][c0 + 2] = bi2;
  s_pv[s3][c0 + 3] = bm3; s_pi[s3][c0 + 3] = bi3;
  __syncthreads();

  if (t < 448) {                    // 14 groups of 8 rows x 32 channels
    const int c = t & 31, g = t >> 5;
    float bv = s_pv[g * 8][c];
    int   bx = s_pi[g * 8][c];
    #pragma unroll
    for (int u = 1; u < 8; ++u) {
      const float v = s_pv[g * 8 + u][c];
      const int   x = s_pi[g * 8 + u][c];
      if (v > bv || (v == bv && x < bx)) { bv = v; bx = x; }
    }
    s2v[g][c] = bv; s2i[g][c] = bx;
  }
  __syncthreads();
  if (t < 32) {
    float bv = s2v[0][t];
    int   bx = s2i[0][t];
    #pragma unroll
    for (int g = 1; g < 14; ++g) {
      const float v = s2v[g][t];
      const int   x = s2i[g][t];
      if (v > bv || (v == bv && x < bx)) { bv = v; bx = x; }
    }
    const int im = bx / 28;
    s_peak[t] = (im << 8) | (bx - im * 28);
  }
  __syncthreads();

  // ---- Phase C: mask the pinned registers, nontemporal store ----
  const int pk0 = s_peak[c0 + 0], pk1 = s_peak[c0 + 1];
  const int pk2 = s_peak[c0 + 2], pk3 = s_peak[c0 + 3];
  const int i0 = s3 / 28;
  const int j0 = s3 - i0 * 28;
  const int im0 = pk0 >> 8, im1 = pk1 >> 8, im2 = pk2 >> 8, im3 = pk3 >> 8;
  // j is constant across the thread's 7 positions: hoist per-channel dj.
  const int dj0 = iabs(j0 - (pk0 & 255));
  const int dj1 = iabs(j0 - (pk1 & 255));
  const int dj2 = iabs(j0 - (pk2 & 255));
  const int dj3 = iabs(j0 - (pk3 & 255));
  constexpr float MS = -(TAU / 7.0f);

#define APPLYK(k) { const int i = i0 + 4 * (k); f32x4 o; \
    o.x = vv##k.x * fmaxf(fmaf((float)(iabs(i - im0) + dj0), MS, TAU), -TAU); \
    o.y = vv##k.y * fmaxf(fmaf((float)(iabs(i - im1) + dj1), MS, TAU), -TAU); \
    o.z = vv##k.z * fmaxf(fmaf((float)(iabs(i - im2) + dj2), MS, TAU), -TAU); \
    o.w = vv##k.w * fmaxf(fmaf((float)(iabs(i - im3) + dj3), MS, TAU), -TAU); \
    __builtin_nontemporal_store(o, dst + (size_t)(k) * KSTR); }
  APPLYK(0) APPLYK(1) APPLYK(2) APPLYK(3) APPLYK(4) APPLYK(5) APPLYK(6)
#undef APPLYK
}

extern "C" void kernel_launch(void* const* d_in, const int* in_sizes, int n_in,
                              void* d_out, int out_size, void* d_ws, size_t ws_size,
                              hipStream_t stream) {
  const f32x4* in4  = (const f32x4*)d_in[0];
  f32x4*       out4 = (f32x4*)d_out;
  // One block per (batch, 32-channel group): 64 x 32 = 2048 blocks, 896 thr.
  fused_mask_kernel<<<BN * 32, 896, 0, stream>>>(in4, out4);
}

// Round 7
// 72.812 us; speedup vs baseline: 1.3409x; 1.0529x over previous
//
#include <hip/hip_runtime.h>

// Problem constants (fixed by the reference)
constexpr int BN  = 64;          // batch
constexpr int HH  = 28;          // height
constexpr int WW  = 28;          // width
constexpr int CC  = 1024;        // channels
constexpr int HWP = HH * WW;     // 784 spatial positions
constexpr int CQ  = CC / 4;      // 256 float4s per spatial position row
constexpr float TAU = 0.5f / 784.0f;

// Native clang vector type (required by __builtin_nontemporal_store).
typedef float f32x4 __attribute__((ext_vector_type(4)));

__device__ __forceinline__ int iabs(int x) { return x < 0 ? -x : x; }

// ---------------------------------------------------------------------------
// Persistent, software-pipelined fused kernel.
// Grid: 512 blocks x 512 threads. Block bk owns batch b = bk>>3 and the four
// 32-channel tiles cg = (bk&7)*4 .. +3 (consecutive -> src/dst advance by +8
// f32x4 per tile). Thread: q = t&7 (channel quad), s3 = t>>3 (64 splits);
// owns p = s3 + 64k, k=0..11, plus k=12 (p = s3+768) for s3<16 (waves 0-1,
// wave-uniform). A wave covers 8 quads x 16 B = 128 B contiguous per position
// (round-5's 64 B line-split doubled FETCH — avoided).
//
// Pipeline per tile: JIT-load k=8..12 -> argmax (consumes regs) -> pin ->
// PREFETCH first 8 float4s of the NEXT tile -> shfl-butterfly reduce +
// tiny-LDS cross-wave reduce (2 barriers) -> mask + nontemporal stores.
// The prefetch overlaps the reduce and store phases, so the block's memory
// pipes never drain (round 4/6 counters: pipes idle during phases was the
// ~30% loss; occupancy alone couldn't cover it).
//
// Reduce: butterfly over lane bits 3,4,5 (the 8 s3-splits within a wave) with
// (v > bv) || (v == bv && x < bx) tie-break, then 8 wave-partials x 32
// channels through 2.2 KB LDS. Exact jnp.argmax first-occurrence semantics.
// Mask: tau * max(1 - 4d/28, -1) == max(fma(d, -tau/7, tau), -tau)
// (~2 ulp of tau; measured absmax 7.6e-6 vs threshold 6.9e-5).
// __launch_bounds__(512, 4): cap VGPR at 128 -> 16 waves/CU (2 blocks).
// ---------------------------------------------------------------------------
__global__ __launch_bounds__(512, 4) void fused_mask_kernel(
    const f32x4* __restrict__ in4, f32x4* __restrict__ out4) {
  __shared__ float s2v[8][32];
  __shared__ int   s2i[8][32];
  __shared__ int   s_peak[32];

  const int t  = threadIdx.x;
  const int q  = t & 7;           // channel quad within the 32-ch tile
  const int s3 = t >> 3;          // position split 0..63
  const int bk = blockIdx.x;
  const int b  = bk >> 3;
  const int cg0 = (bk & 7) * 4;   // first of 4 consecutive channel-groups

  constexpr size_t KSTR = (size_t)64 * CQ;   // 64 positions per k-step

  const f32x4* sp = in4  + ((size_t)b * HWP + s3) * CQ + cg0 * 8 + q;
  f32x4*       dp = out4 + ((size_t)b * HWP + s3) * CQ + cg0 * 8 + q;

  const bool tail = (s3 < 16);    // wave-uniform (waves 0,1)
  const int  i0 = s3 / 28;
  const int  j0 = s3 - 28 * i0;
  const int  c0 = q * 4;
  constexpr float MS = -(TAU / 7.0f);

  f32x4 A0, A1, A2, A3, A4, A5, A6, A7;   // prefetch buffer A
  f32x4 B0, B1, B2, B3, B4, B5, B6, B7;   // prefetch buffer B
  f32x4 X8, X9, X10, X11;                 // JIT part (k=8..11), reused per tile
  f32x4 XT = {0.0f, 0.0f, 0.0f, 0.0f};    // tail (k=12), reused per tile

  // Prologue: prefetch first 8 float4s of tile 0 into A.
  A0 = sp[0 * KSTR]; A1 = sp[1 * KSTR]; A2 = sp[2 * KSTR]; A3 = sp[3 * KSTR];
  A4 = sp[4 * KSTR]; A5 = sp[5 * KSTR]; A6 = sp[6 * KSTR]; A7 = sp[7 * KSTR];

  // Per-channel test with first-occurrence (ascending p, strict '>').
#define AM(v, k) { const int p = s3 + 64 * (k); \
    if (v.x > bm0) { bm0 = v.x; bi0 = p; } \
    if (v.y > bm1) { bm1 = v.y; bi1 = p; } \
    if (v.z > bm2) { bm2 = v.z; bi2 = p; } \
    if (v.w > bm3) { bm3 = v.w; bi3 = p; } }

  // Butterfly over the wave's 8 s3-splits (lane xor 8,16,32), min-idx ties.
#define RED(bv, bx) { \
    _Pragma("unroll") \
    for (int st = 8; st < 64; st <<= 1) { \
      const float ov = __shfl_xor(bv, st, 64); \
      const int   ox = __shfl_xor(bx, st, 64); \
      if (ov > bv || (ov == bv && ox < bx)) { bv = ov; bx = ox; } \
    } }

  // Mask + nontemporal store one f32x4; advances (i,j) by p += 64.
#define APK(v, off) { f32x4 o; \
    o.x = v.x * fmaxf(fmaf((float)(iabs(i - im0) + iabs(j - jm0)), MS, TAU), -TAU); \
    o.y = v.y * fmaxf(fmaf((float)(iabs(i - im1) + iabs(j - jm1)), MS, TAU), -TAU); \
    o.z = v.z * fmaxf(fmaf((float)(iabs(i - im2) + iabs(j - jm2)), MS, TAU), -TAU); \
    o.w = v.w * fmaxf(fmaf((float)(iabs(i - im3) + iabs(j - jm3)), MS, TAU), -TAU); \
    __builtin_nontemporal_store(o, dp + (off)); \
    j += 8; i += 2; if (j >= 28) { j -= 28; ++i; } }

#define TILE(CUR, NXT, PF) { \
    /* JIT loads for k=8..12 (issued first so the argmax waitcnt need not */ \
    /* drain the later prefetch) */ \
    X8  = sp[ 8 * KSTR]; X9  = sp[ 9 * KSTR]; \
    X10 = sp[10 * KSTR]; X11 = sp[11 * KSTR]; \
    if (tail) XT = sp[12 * KSTR]; \
    float bm0 = -__builtin_inff(), bm1 = bm0, bm2 = bm0, bm3 = bm0; \
    int   bi0 = s3, bi1 = s3, bi2 = s3, bi3 = s3; \
    AM(CUR##0, 0) AM(CUR##1, 1) AM(CUR##2, 2) AM(CUR##3, 3) \
    AM(CUR##4, 4) AM(CUR##5, 5) AM(CUR##6, 6) AM(CUR##7, 7) \
    AM(X8, 8) AM(X9, 9) AM(X10, 10) AM(X11, 11) \
    if (tail) { const int p = s3 + 768; \
      if (XT.x > bm0) { bm0 = XT.x; bi0 = p; } \
      if (XT.y > bm1) { bm1 = XT.y; bi1 = p; } \
      if (XT.z > bm2) { bm2 = XT.z; bi2 = p; } \
      if (XT.w > bm3) { bm3 = XT.w; bi3 = p; } } \
    /* pin the consumed values so the compiler cannot re-load them at the */ \
    /* store (keeps the register pipeline honest) */ \
    asm volatile("" : "+v"(CUR##0), "+v"(CUR##1), "+v"(CUR##2), "+v"(CUR##3), \
                      "+v"(CUR##4), "+v"(CUR##5), "+v"(CUR##6), "+v"(CUR##7), \
                      "+v"(X8), "+v"(X9), "+v"(X10), "+v"(X11)); \
    /* prefetch next tile (same rows, +8 f32x4 = next 32 channels) — these */ \
    /* overlap the reduce barriers and the store loop below */ \
    if (PF) { \
      NXT##0 = sp[8 + 0 * KSTR]; NXT##1 = sp[8 + 1 * KSTR]; \
      NXT##2 = sp[8 + 2 * KSTR]; NXT##3 = sp[8 + 3 * KSTR]; \
      NXT##4 = sp[8 + 4 * KSTR]; NXT##5 = sp[8 + 5 * KSTR]; \
      NXT##6 = sp[8 + 6 * KSTR]; NXT##7 = sp[8 + 7 * KSTR]; \
    } \
    /* in-wave butterfly, then 8 wave-partials through tiny LDS */ \
    RED(bm0, bi0) RED(bm1, bi1) RED(bm2, bi2) RED(bm3, bi3) \
    if ((t & 56) == 0) { const int w = t >> 6; \
      s2v[w][c0 + 0] = bm0; s2i[w][c0 + 0] = bi0; \
      s2v[w][c0 + 1] = bm1; s2i[w][c0 + 1] = bi1; \
      s2v[w][c0 + 2] = bm2; s2i[w][c0 + 2] = bi2; \
      s2v[w][c0 + 3] = bm3; s2i[w][c0 + 3] = bi3; } \
    __syncthreads(); \
    if (t < 32) { \
      float bv = s2v[0][t]; int bx = s2i[0][t]; \
      _Pragma("unroll") \
      for (int g = 1; g < 8; ++g) { \
        const float v = s2v[g][t]; const int x = s2i[g][t]; \
        if (v > bv || (v == bv && x < bx)) { bv = v; bx = x; } } \
      const int im = bx / 28; \
      s_peak[t] = (im << 8) | (bx - 28 * im); } \
    __syncthreads(); \
    /* mask + store (overlapped by the in-flight prefetch) */ \
    { const int pk0 = s_peak[c0 + 0], pk1 = s_peak[c0 + 1]; \
      const int pk2 = s_peak[c0 + 2], pk3 = s_peak[c0 + 3]; \
      const int im0 = pk0 >> 8, jm0 = pk0 & 255; \
      const int im1 = pk1 >> 8, jm1 = pk1 & 255; \
      const int im2 = pk2 >> 8, jm2 = pk2 & 255; \
      const int im3 = pk3 >> 8, jm3 = pk3 & 255; \
      int i = i0, j = j0; \
      APK(CUR##0, 0 * KSTR) APK(CUR##1, 1 * KSTR) APK(CUR##2, 2 * KSTR) \
      APK(CUR##3, 3 * KSTR) APK(CUR##4, 4 * KSTR) APK(CUR##5, 5 * KSTR) \
      APK(CUR##6, 6 * KSTR) APK(CUR##7, 7 * KSTR) \
      APK(X8, 8 * KSTR) APK(X9, 9 * KSTR) APK(X10, 10 * KSTR) APK(X11, 11 * KSTR) \
      if (tail) { f32x4 o; \
        o.x = XT.x * fmaxf(fmaf((float)(iabs(i - im0) + iabs(j - jm0)), MS, TAU), -TAU); \
        o.y = XT.y * fmaxf(fmaf((float)(iabs(i - im1) + iabs(j - jm1)), MS, TAU), -TAU); \
        o.z = XT.z * fmaxf(fmaf((float)(iabs(i - im2) + iabs(j - jm2)), MS, TAU), -TAU); \
        o.w = XT.w * fmaxf(fmaf((float)(iabs(i - im3) + iabs(j - jm3)), MS, TAU), -TAU); \
        __builtin_nontemporal_store(o, dp + 12 * KSTR); } \
    } }
  // NOTE on LDS reuse across tiles without a 3rd barrier: s_peak reads happen
  // before the stores (program order), and the next tile writes s2v before
  // its first barrier but writes s_peak only after it — no hazard.

  TILE(A, B, true)  sp += 8; dp += 8;   // tile 0, prefetch tile 1
  TILE(B, A, true)  sp += 8; dp += 8;   // tile 1, prefetch tile 2
  TILE(A, B, true)  sp += 8; dp += 8;   // tile 2, prefetch tile 3
  TILE(B, A, false)                      // tile 3, no prefetch

#undef TILE
#undef APK
#undef RED
#undef AM
}

extern "C" void kernel_launch(void* const* d_in, const int* in_sizes, int n_in,
                              void* d_out, int out_size, void* d_ws, size_t ws_size,
                              hipStream_t stream) {
  const f32x4* in4  = (const f32x4*)d_in[0];
  f32x4*       out4 = (f32x4*)d_out;
  // 512 persistent blocks x 512 threads; each block does 4 consecutive tiles.
  fused_mask_kernel<<<512, 512, 0, stream>>>(in4, out4);
}